// Round 8
// baseline (406.726 us; speedup 1.0000x reference)
//
#include <hip/hip_runtime.h>

#define N_TOK   16384
#define K_CODES 8192
#define DIMS    256

// d_out offsets (floats): out, loss, idx, new_cluster_size, new_ema_w, new_embedding
#define OUT_OFF  0
#define LOSS_OFF 4194304
#define IDX_OFF  4194305
#define NCS_OFF  4210689
#define NEMA_OFF 4218881
#define NEMB_OFF 6316033

// ws byte offsets
#define WS_ZFRAG  0u          // ushort frag-order [512 tg][2 lv][16 ks][64 lane][8] = 16 MB
#define WS_EFRAG  16777216u   // ushort frag-order [256 g][2 lv][16 ks][64 lane][8] = 8 MB
#define WS_ENORM  25165824u   // f32 [8192]
#define WS_AMIN   25198592u   // u64 [16384] packed (score|idx); +131072: 2 barrier ints
#define WS_IDXI   25722880u   // int [16384]
#define WS_CNT    25788416u   // int [8192]
#define WS_CS     25821184u   // f32 [8192]
#define WS_OFFS   25853952u   // int [8192]
#define WS_WPOS   25886720u   // int [8192]
#define WS_TLIST  25919488u   // int [16384]
#define WS_DENOM  25985024u   // double

typedef _Float16 f16x8 __attribute__((ext_vector_type(8)));
typedef float    f32x16 __attribute__((ext_vector_type(16)));

union HU { _Float16 h; unsigned short u; };

static __device__ inline void split_f32(float x, unsigned short& hi, unsigned short& lo) {
    HU a; a.h = (_Float16)x;                    // RNE f32->f16
    float r = (x - (float)a.h) * 2048.0f;       // exact residual, scaled to normal range
    HU b; b.h = (_Float16)r;
    hi = a.u; lo = b.u;
}

static __device__ inline float join_f16(unsigned short h, unsigned short l) {
    HU a, b; a.u = h; b.u = l;
    return (float)a.h + (float)b.h * 4.8828125e-4f;
}

// async global->LDS, 16B per lane; LDS dest = wave-uniform base + lane*16
#define GLD16(gp, lp) __builtin_amdgcn_global_load_lds( \
    (const __attribute__((address_space(1))) unsigned int*)(gp), \
    (__attribute__((address_space(3))) unsigned int*)(lp), 16, 0, 0)

// ---- fused: cvt_z (blocks 0-1023) + cvt_e/enorm/init (blocks 1024-1279) ----
__global__ __launch_bounds__(256) void fused_cvt(
    const float* __restrict__ z, unsigned short* __restrict__ zfrag,
    float* __restrict__ loss_cell, double* __restrict__ denom,
    const float* __restrict__ emb, unsigned short* __restrict__ efrag,
    float* __restrict__ enorm, int* __restrict__ cnt,
    unsigned long long* __restrict__ amin, int* __restrict__ bar) {
    const int t = threadIdx.x;
    if (blockIdx.x < 1024) {
        // ---- cvt_z: z [16][256][1024] f32 -> zfrag (frag-order, 2-level split) ----
        __shared__ float T[64][65];
        const int hg = blockIdx.x & 15, dg = (blockIdx.x >> 4) & 3, b = blockIdx.x >> 6;
        if (blockIdx.x == 0 && t == 0) { *loss_cell = 0.f; *denom = 0.0; }
        const int c4 = (t & 15) * 4, r0 = t >> 4;
        const float* zb = z + (((size_t)(b * 256 + dg * 64)) << 10) + hg * 64;
#pragma unroll
        for (int p = 0; p < 4; ++p) {
            const int r = r0 + p * 16;
            const float4 v = *(const float4*)(zb + ((size_t)r << 10) + c4);
            T[r][c4] = v.x; T[r][c4 + 1] = v.y; T[r][c4 + 2] = v.z; T[r][c4 + 3] = v.w;
        }
        __syncthreads();
        const int tr = t & 63, dc = (t >> 6) * 16;   // token-local tr, 16-dim chunk dc
        const int tile = b * 16 + hg;
        const int tg = tile * 2 + (tr >> 5), l31 = tr & 31;
        const int ks = dg * 4 + (dc >> 4);
        unsigned short hb[16], lb[16];
#pragma unroll
        for (int j = 0; j < 16; ++j) split_f32(T[dc + j][tr], hb[j], lb[j]);
#pragma unroll
        for (int lv = 0; lv < 2; ++lv) {
            const unsigned short* src = lv ? lb : hb;
            unsigned short* dst = zfrag + (size_t)((tg * 2 + lv) * 16 + ks) * 512;
            *(uint4*)(dst + l31 * 8)       = ((const uint4*)src)[0];   // khalf 0 (j 0..7)
            *(uint4*)(dst + 256 + l31 * 8) = ((const uint4*)src)[1];   // khalf 1 (j 8..15)
        }
    } else {
        // ---- cvt_e: emb -> efrag + ||e||^2 (f64); zero cnt/bar; init amin ----
        __shared__ double red[256];
        const int g = blockIdx.x - 1024;
        const int lane = t & 63, q = t >> 6;
        const int l31 = lane & 31, lhi = lane >> 5;
        if (g < 32) cnt[g * 256 + t] = 0;
        if (g < 64) amin[g * 256 + t] = 0xFFFFFFFFFFFFFFFFull;
        if (g == 0 && t < 2) bar[t] = 0;
        const float* rowp = emb + (size_t)(g * 32 + l31) * 256 + lhi * 8;
        double s = 0.0;
#pragma unroll
        for (int kk = 0; kk < 4; ++kk) {
            const int ks = q * 4 + kk;
            const float4 a = *(const float4*)(rowp + ks * 16);
            const float4 bq = *(const float4*)(rowp + ks * 16 + 4);
            const float vv[8] = {a.x, a.y, a.z, a.w, bq.x, bq.y, bq.z, bq.w};
            unsigned short hb[8], lb[8];
#pragma unroll
            for (int j = 0; j < 8; ++j) {
                split_f32(vv[j], hb[j], lb[j]);
                s += (double)vv[j] * (double)vv[j];
            }
            *(uint4*)(efrag + (size_t)((g * 2 + 0) * 16 + ks) * 512 + lane * 8) = *(const uint4*)hb;
            *(uint4*)(efrag + (size_t)((g * 2 + 1) * 16 + ks) * 512 + lane * 8) = *(const uint4*)lb;
        }
        red[t] = s;
        __syncthreads();
        if (t < 32) {
            double acc = 0.0;
#pragma unroll
            for (int qq = 0; qq < 4; ++qq) acc += red[qq * 64 + t] + red[qq * 64 + 32 + t];
            enorm[g * 32 + t] = (float)acc;
        }
    }
}

// ---- MFMA argmin (r6-proven, 185 us): block = 128 tokens x 64-code chunks ----
// All waves share the staged 64 codes; Z register-resident; E 2x16KB ping-pong;
// 3-pass MFMA issue; packed u64 atomicMin epilogue (lexicographic == (score,idx)).
__global__ __launch_bounds__(256, 2) void argmin_mfma(
    const unsigned short* __restrict__ zfrag, const unsigned short* __restrict__ efrag,
    const float* __restrict__ enorm, unsigned long long* __restrict__ amin) {
    __shared__ __align__(16) unsigned short E[2][8192];   // [buf][slot(lv*2+cg)*4+ksl][lane*8]
    __shared__ float en_s[2][64];

    const int tid = threadIdx.x, lane = tid & 63, wave = tid >> 6;
    const int tile = blockIdx.x & 127, csplit = blockIdx.x >> 7;
    const int token0 = tile * 128, code0 = csplit * 2048;

    // register-resident Z frags for this wave's 32-token group
    f16x8 Zr[2][16];
    {
        const unsigned short* zb = zfrag + (size_t)(tile * 4 + wave) * 16384 + lane * 8;
#pragma unroll
        for (int lv = 0; lv < 2; ++lv)
#pragma unroll
            for (int ks = 0; ks < 16; ++ks)
                Zr[lv][ks] = *(const f16x8*)(zb + (lv * 16 + ks) * 512);
    }

    const int slv = wave >> 1, scg = wave & 1;   // this wave stages (level slv, code-group scg)

    float bv = 3.4e38f; int bi = 0;

    // prologue: chunk (ct=0, kc=0) -> buf 0; en_s[0]
#pragma unroll
    for (int ksl = 0; ksl < 4; ++ksl) {
        const unsigned short* sp = efrag +
            (size_t)(((csplit * 64 + scg) * 2 + slv) * 16 + ksl) * 512 + lane * 8;
        GLD16(sp, &E[0][(wave * 4 + ksl) * 512]);
    }
    if (tid < 64) en_s[0][tid] = enorm[code0 + tid];
    __syncthreads();

    for (int ct = 0; ct < 32; ++ct) {
        f32x16 acc_h[2], acc_l[2];
#pragma unroll
        for (int cg = 0; cg < 2; ++cg)
#pragma unroll
            for (int qq = 0; qq < 16; ++qq) { acc_h[cg][qq] = 0.f; acc_l[cg][qq] = 0.f; }

#pragma unroll
        for (int kc = 0; kc < 4; ++kc) {
            const int p = (ct * 4 + kc) & 1;
            if (!(ct == 31 && kc == 3)) {
                const int nch = ct * 4 + kc + 1;
                const int nct = nch >> 2, nkc = nch & 3;
                const int g = csplit * 64 + nct * 2 + scg;
#pragma unroll
                for (int ksl = 0; ksl < 4; ++ksl) {
                    const unsigned short* sp = efrag +
                        (size_t)((g * 2 + slv) * 16 + nkc * 4 + ksl) * 512 + lane * 8;
                    GLD16(sp, &E[p ^ 1][(wave * 4 + ksl) * 512]);
                }
            }
            if (kc == 0 && ct < 31 && tid < 64)
                en_s[(ct + 1) & 1][tid] = enorm[code0 + (ct + 1) * 64 + tid];

#pragma unroll
            for (int ksl = 0; ksl < 4; ++ksl) {
                const int ks = kc * 4 + ksl;
                f16x8 ae[2][2];
#pragma unroll
                for (int lv = 0; lv < 2; ++lv)
#pragma unroll
                    for (int cg = 0; cg < 2; ++cg)
                        ae[lv][cg] = *(const f16x8*)&E[p][((lv * 2 + cg) * 4 + ksl) * 512 + lane * 8];
                // three passes; per-accumulator order identical to the proven kernel
#pragma unroll
                for (int cg = 0; cg < 2; ++cg)
                    acc_h[cg] = __builtin_amdgcn_mfma_f32_32x32x16_f16(ae[0][cg], Zr[0][ks], acc_h[cg], 0, 0, 0);
#pragma unroll
                for (int cg = 0; cg < 2; ++cg)
                    acc_l[cg] = __builtin_amdgcn_mfma_f32_32x32x16_f16(ae[0][cg], Zr[1][ks], acc_l[cg], 0, 0, 0);
#pragma unroll
                for (int cg = 0; cg < 2; ++cg)
                    acc_l[cg] = __builtin_amdgcn_mfma_f32_32x32x16_f16(ae[1][cg], Zr[0][ks], acc_l[cg], 0, 0, 0);
            }
            if (kc == 3) {
                // score = ||e||^2 - 2*(hi + lo/2048); per-lane running argmin (k ascending)
                const int rbase = 4 * (lane >> 5);
#pragma unroll
                for (int cg = 0; cg < 2; ++cg)
#pragma unroll
                    for (int r = 0; r < 16; ++r) {
                        const int cl = cg * 32 + (r & 3) + 8 * (r >> 2) + rbase;
                        const float s = en_s[ct & 1][cl] -
                            2.0f * (acc_h[cg][r] + acc_l[cg][r] * 4.8828125e-4f);
                        const int code = code0 + ct * 64 + cl;
                        if (s < bv) { bv = s; bi = code; }
                    }
            }
            __syncthreads();
        }
    }
    // lanes l and l^32 hold the same token (different code row-halves)
    {
        const float ov = __shfl_xor(bv, 32);
        const int   oi = __shfl_xor(bi, 32);
        if (ov < bv || (ov == bv && oi < bi)) { bv = ov; bi = oi; }
    }
    if (lane < 32) {
        const int n = token0 + wave * 32 + lane;
        unsigned int u = __float_as_uint(bv);
        u = (u & 0x80000000u) ? ~u : (u | 0x80000000u);   // order-preserving f32->u32
        const unsigned long long pk = ((unsigned long long)u << 32) | (unsigned int)bi;
        atomicMin(&amin[n], pk);
    }
}

// ---- fused post: idx/cnt -> [grid barrier] -> scan (blk 0) || cs/denom (blk 1-32)
//      -> [grid barrier] -> scatter. 64 blocks (all co-resident on 256 CUs; the
//      previous kernel fully drains before dispatch, so the software barrier
//      cannot deadlock). Token k stays in-register across phases; cross-block
//      reads of atomically-written cnt use device-scope atomic loads.
__global__ __launch_bounds__(256) void post_kernel(
    const unsigned long long* __restrict__ amin,
    int* __restrict__ idx_i, float* __restrict__ idx_f,
    int* __restrict__ cnt, int* __restrict__ offs, int* __restrict__ wpos,
    int* __restrict__ tlist, const float* __restrict__ cluster_size,
    float* __restrict__ cs, double* __restrict__ denom, int* __restrict__ bar) {
    const int t = threadIdx.x, b = blockIdx.x;
    const int n = b * 256 + t;
    const int k = (int)(unsigned int)(amin[n] & 0xFFFFFFFFull);
    idx_i[n] = k;
    idx_f[n] = (float)k;
    atomicAdd(&cnt[k], 1);

    // ---- grid barrier 1 ----
    __threadfence();
    __syncthreads();
    if (t == 0) {
        atomicAdd(&bar[0], 1);
        while (__hip_atomic_load(&bar[0], __ATOMIC_RELAXED, __HIP_MEMORY_SCOPE_AGENT) < 64) {}
    }
    __syncthreads();

    if (b == 0) {
        // exclusive scan of 8192 counts -> offs, wpos
        __shared__ int part[256];
        const int base = t * 32;
        int loc[32]; int s = 0;
#pragma unroll
        for (int j = 0; j < 32; ++j) {
            loc[j] = __hip_atomic_load(&cnt[base + j], __ATOMIC_RELAXED, __HIP_MEMORY_SCOPE_AGENT);
            s += loc[j];
        }
        part[t] = s;
        __syncthreads();
        for (int off = 1; off < 256; off <<= 1) {
            int v = 0;
            if (t >= off) v = part[t - off];
            __syncthreads();
            if (t >= off) part[t] += v;
            __syncthreads();
        }
        int run = (t > 0) ? part[t - 1] : 0;
#pragma unroll
        for (int j = 0; j < 32; ++j) {
            offs[base + j] = run;
            wpos[base + j] = run;
            run += loc[j];
        }
    } else if (b <= 32) {
        // cs + denom (overlaps with block 0's scan)
        __shared__ double red[256];
        const int k2 = (b - 1) * 256 + t;
        const int c = __hip_atomic_load(&cnt[k2], __ATOMIC_RELAXED, __HIP_MEMORY_SCOPE_AGENT);
        const float v = cluster_size[k2] * 0.99f + 0.01f * (float)c + 1e-5f;
        cs[k2] = v;
        red[t] = (double)v;
        __syncthreads();
        for (int s2 = 128; s2; s2 >>= 1) {
            if (t < s2) red[t] += red[t + s2];
            __syncthreads();
        }
        if (t == 0) atomicAdd(denom, red[0]);
    }

    // ---- grid barrier 2 (wpos visible to all) ----
    __threadfence();
    __syncthreads();
    if (t == 0) {
        atomicAdd(&bar[1], 1);
        while (__hip_atomic_load(&bar[1], __ATOMIC_RELAXED, __HIP_MEMORY_SCOPE_AGENT) < 64) {}
    }
    __syncthreads();

    tlist[atomicAdd(&wpos[k], 1)] = n;
}

// ---- fused: nema_finalize (blocks 0-2047, 4 codes each) + gather/loss (2048-3071) ----
__global__ __launch_bounds__(256) void nema_gather(
    const unsigned short* __restrict__ zfrag,
    const int* __restrict__ offs, const int* __restrict__ cnt, const int* __restrict__ tlist,
    const float* __restrict__ ema_w, const float* __restrict__ cs,
    const double* __restrict__ denom, float* __restrict__ ncs_out,
    float* __restrict__ nema_out, float* __restrict__ nemb_out,
    const float* __restrict__ z, const float* __restrict__ emb,
    const int* __restrict__ idx_i, float* __restrict__ out, float* __restrict__ loss_cell) {
    __shared__ float redf[256];
    const int t = threadIdx.x;
    if (blockIdx.x < 2048) {
        const int lane = t & 63, wave = t >> 6;
        const int k = blockIdx.x * 4 + wave;
        const int l31 = lane & 31, sel = lane >> 5;  // sel: 0 = hi loader, 1 = lo loader
        const int beg = offs[k], c = cnt[k];
        float acc[8] = {0.f, 0.f, 0.f, 0.f, 0.f, 0.f, 0.f, 0.f};
        const size_t lidx = (size_t)((l31 >> 1) + sel * 16) * 512 + (l31 & 1) * 256;
        int i = 0;
        for (; i + 1 < c; i += 2) {      // 2-way unroll: independent load/shfl chains
            const int tokA = tlist[beg + i], tokB = tlist[beg + i + 1];
            const uint4 vA = *(const uint4*)(zfrag + (size_t)(tokA >> 5) * 16384 + lidx + (tokA & 31) * 8);
            const uint4 vB = *(const uint4*)(zfrag + (size_t)(tokB >> 5) * 16384 + lidx + (tokB & 31) * 8);
            uint4 oA, oB;
            oA.x = __shfl_xor((int)vA.x, 32); oA.y = __shfl_xor((int)vA.y, 32);
            oA.z = __shfl_xor((int)vA.z, 32); oA.w = __shfl_xor((int)vA.w, 32);
            oB.x = __shfl_xor((int)vB.x, 32); oB.y = __shfl_xor((int)vB.y, 32);
            oB.z = __shfl_xor((int)vB.z, 32); oB.w = __shfl_xor((int)vB.w, 32);
            if (lane < 32) {
                const unsigned short* hA = (const unsigned short*)&vA;
                const unsigned short* lA = (const unsigned short*)&oA;
                const unsigned short* hB = (const unsigned short*)&vB;
                const unsigned short* lB = (const unsigned short*)&oB;
#pragma unroll
                for (int j = 0; j < 8; ++j)
                    acc[j] += join_f16(hA[j], lA[j]) + join_f16(hB[j], lB[j]);
            }
        }
        if (i < c) {
            const int tok = tlist[beg + i];
            const uint4 v = *(const uint4*)(zfrag + (size_t)(tok >> 5) * 16384 + lidx + (tok & 31) * 8);
            uint4 o;
            o.x = __shfl_xor((int)v.x, 32); o.y = __shfl_xor((int)v.y, 32);
            o.z = __shfl_xor((int)v.z, 32); o.w = __shfl_xor((int)v.w, 32);
            if (lane < 32) {
                const unsigned short* hp = (const unsigned short*)&v;
                const unsigned short* lp = (const unsigned short*)&o;
#pragma unroll
                for (int j = 0; j < 8; ++j) acc[j] += join_f16(hp[j], lp[j]);
            }
        }
        const float dn = (float)(*denom) + (float)K_CODES * 1e-5f;
        const float ncs = cs[k] / dn;
        if (lane == 0) ncs_out[k] = ncs;
        if (lane < 32) {
            const size_t off = ((size_t)k << 8) + l31 * 8;
#pragma unroll
            for (int j = 0; j < 8; ++j) {
                const float ne = ema_w[off + j] * 0.99f + 0.01f * acc[j];
                nema_out[off + j] = ne;
                nemb_out[off + j] = ne / ncs;
            }
        }
    } else {
        const int gb = blockIdx.x - 2048;
        const int n0 = (gb >> 2) * 64;
        const int dg = (gb & 3) * 64;
        const int b = n0 >> 10, hw0 = n0 & 1023;
        const int lane = t & 63, w = t >> 6;
        const int n = n0 + lane;
        const int k = idx_i[n];
        const float* zb = z + ((size_t)b << 18) + hw0 + lane;
        float* ob = out + ((size_t)b << 18) + hw0 + lane;
        float ls = 0.f;
#pragma unroll 4
        for (int d = dg + w; d < dg + 64; d += 4) {
            const float zv = zb[(size_t)d << 10];
            const float ev = emb[((size_t)k << 8) + d];
            ob[(size_t)d << 10] = ev;
            const float df = ev - zv;
            ls += df * df;
        }
        redf[t] = ls;
        __syncthreads();
        for (int s2 = 128; s2; s2 >>= 1) {
            if (t < s2) redf[t] += redf[t + s2];
            __syncthreads();
        }
        if (t == 0) atomicAdd(loss_cell, redf[0] * (0.25f / 4194304.0f));
    }
}

// ---------------- launch ----------------
extern "C" void kernel_launch(void* const* d_in, const int* in_sizes, int n_in,
                              void* d_out, int out_size, void* d_ws, size_t ws_size,
                              hipStream_t stream) {
    const float* z            = (const float*)d_in[0];
    const float* emb          = (const float*)d_in[1];
    const float* cluster_size = (const float*)d_in[2];
    const float* ema_w        = (const float*)d_in[3];
    float* out = (float*)d_out;
    char*  wsb = (char*)d_ws;

    unsigned short* zfrag = (unsigned short*)(wsb + WS_ZFRAG);
    unsigned short* efrag = (unsigned short*)(wsb + WS_EFRAG);
    float*  enorm  = (float*)(wsb + WS_ENORM);
    unsigned long long* amin = (unsigned long long*)(wsb + WS_AMIN);
    int*    bar    = (int*)(wsb + WS_AMIN + 131072);   // spare space in old PVAL region
    int*    idx_i  = (int*)(wsb + WS_IDXI);
    int*    cnt    = (int*)(wsb + WS_CNT);
    float*  cs     = (float*)(wsb + WS_CS);
    int*    offs   = (int*)(wsb + WS_OFFS);
    int*    wpos   = (int*)(wsb + WS_WPOS);
    int*    tlist  = (int*)(wsb + WS_TLIST);
    double* denom  = (double*)(wsb + WS_DENOM);

    fused_cvt<<<1280, 256, 0, stream>>>(z, zfrag, out + LOSS_OFF, denom,
                                        emb, efrag, enorm, cnt, amin, bar);
    argmin_mfma<<<512, 256, 0, stream>>>(zfrag, efrag, enorm, amin);
    post_kernel<<<64, 256, 0, stream>>>(amin, idx_i, out + IDX_OFF, cnt, offs, wpos,
                                        tlist, cluster_size, cs, denom, bar);
    nema_gather<<<3072, 256, 0, stream>>>(zfrag, offs, cnt, tlist, ema_w, cs, denom,
                                          out + NCS_OFF, out + NEMA_OFF, out + NEMB_OFF,
                                          z, emb, idx_i, out + OUT_OFF, out + LOSS_OFF);
}

// Round 9
// 376.728 us; speedup vs baseline: 1.0796x; 1.0796x over previous
//
#include <hip/hip_runtime.h>

#define N_TOK   16384
#define K_CODES 8192
#define DIMS    256

// d_out offsets (floats): out, loss, idx, new_cluster_size, new_ema_w, new_embedding
#define OUT_OFF  0
#define LOSS_OFF 4194304
#define IDX_OFF  4194305
#define NCS_OFF  4210689
#define NEMA_OFF 4218881
#define NEMB_OFF 6316033

// ws byte offsets
#define WS_ZFRAG  0u          // ushort frag-order [512 tg][2 lv][16 ks][64 lane][8] = 16 MB
#define WS_EFRAG  16777216u   // ushort frag-order [256 g][2 lv][16 ks][64 lane][8] = 8 MB
#define WS_ENORM  25165824u   // f32 [8192]
#define WS_AMIN   25198592u   // u64 [16384] packed (score|idx) argmin cells
#define WS_IDXI   25722880u   // int [16384]
#define WS_CNT    25788416u   // int [8192]
#define WS_CS     25821184u   // f32 [8192]
#define WS_OFFS   25853952u   // int [8192]
#define WS_WPOS   25886720u   // int [8192]
#define WS_TLIST  25919488u   // int [16384]
#define WS_DENOM  25985024u   // double

typedef _Float16 f16x8 __attribute__((ext_vector_type(8)));
typedef float    f32x16 __attribute__((ext_vector_type(16)));

union HU { _Float16 h; unsigned short u; };

static __device__ inline void split_f32(float x, unsigned short& hi, unsigned short& lo) {
    HU a; a.h = (_Float16)x;                    // RNE f32->f16
    float r = (x - (float)a.h) * 2048.0f;       // exact residual, scaled to normal range
    HU b; b.h = (_Float16)r;
    hi = a.u; lo = b.u;
}

static __device__ inline float join_f16(unsigned short h, unsigned short l) {
    HU a, b; a.u = h; b.u = l;
    return (float)a.h + (float)b.h * 4.8828125e-4f;
}

// async global->LDS, 16B per lane; LDS dest = wave-uniform base + lane*16
#define GLD16(gp, lp) __builtin_amdgcn_global_load_lds( \
    (const __attribute__((address_space(1))) unsigned int*)(gp), \
    (__attribute__((address_space(3))) unsigned int*)(lp), 16, 0, 0)

// ---- fused: cvt_z (blocks 0-1023) + cvt_e/enorm/init (blocks 1024-1279) ----
__global__ __launch_bounds__(256) void fused_cvt(
    const float* __restrict__ z, unsigned short* __restrict__ zfrag,
    float* __restrict__ loss_cell, double* __restrict__ denom,
    const float* __restrict__ emb, unsigned short* __restrict__ efrag,
    float* __restrict__ enorm, int* __restrict__ cnt,
    unsigned long long* __restrict__ amin) {
    const int t = threadIdx.x;
    if (blockIdx.x < 1024) {
        // ---- cvt_z: z [16][256][1024] f32 -> zfrag (frag-order, 2-level split) ----
        __shared__ float T[64][65];
        const int hg = blockIdx.x & 15, dg = (blockIdx.x >> 4) & 3, b = blockIdx.x >> 6;
        if (blockIdx.x == 0 && t == 0) { *loss_cell = 0.f; *denom = 0.0; }
        const int c4 = (t & 15) * 4, r0 = t >> 4;
        const float* zb = z + (((size_t)(b * 256 + dg * 64)) << 10) + hg * 64;
#pragma unroll
        for (int p = 0; p < 4; ++p) {
            const int r = r0 + p * 16;
            const float4 v = *(const float4*)(zb + ((size_t)r << 10) + c4);
            T[r][c4] = v.x; T[r][c4 + 1] = v.y; T[r][c4 + 2] = v.z; T[r][c4 + 3] = v.w;
        }
        __syncthreads();
        const int tr = t & 63, dc = (t >> 6) * 16;   // token-local tr, 16-dim chunk dc
        const int tile = b * 16 + hg;
        const int tg = tile * 2 + (tr >> 5), l31 = tr & 31;
        const int ks = dg * 4 + (dc >> 4);
        unsigned short hb[16], lb[16];
#pragma unroll
        for (int j = 0; j < 16; ++j) split_f32(T[dc + j][tr], hb[j], lb[j]);
#pragma unroll
        for (int lv = 0; lv < 2; ++lv) {
            const unsigned short* src = lv ? lb : hb;
            unsigned short* dst = zfrag + (size_t)((tg * 2 + lv) * 16 + ks) * 512;
            *(uint4*)(dst + l31 * 8)       = ((const uint4*)src)[0];   // khalf 0 (j 0..7)
            *(uint4*)(dst + 256 + l31 * 8) = ((const uint4*)src)[1];   // khalf 1 (j 8..15)
        }
    } else {
        // ---- cvt_e: emb -> efrag + ||e||^2 (f64); zero cnt; init amin to +inf ----
        __shared__ double red[256];
        const int g = blockIdx.x - 1024;
        const int lane = t & 63, q = t >> 6;
        const int l31 = lane & 31, lhi = lane >> 5;
        if (g < 32) cnt[g * 256 + t] = 0;
        if (g < 64) amin[g * 256 + t] = 0xFFFFFFFFFFFFFFFFull;
        const float* rowp = emb + (size_t)(g * 32 + l31) * 256 + lhi * 8;
        double s = 0.0;
#pragma unroll
        for (int kk = 0; kk < 4; ++kk) {
            const int ks = q * 4 + kk;
            const float4 a = *(const float4*)(rowp + ks * 16);
            const float4 bq = *(const float4*)(rowp + ks * 16 + 4);
            const float vv[8] = {a.x, a.y, a.z, a.w, bq.x, bq.y, bq.z, bq.w};
            unsigned short hb[8], lb[8];
#pragma unroll
            for (int j = 0; j < 8; ++j) {
                split_f32(vv[j], hb[j], lb[j]);
                s += (double)vv[j] * (double)vv[j];
            }
            *(uint4*)(efrag + (size_t)((g * 2 + 0) * 16 + ks) * 512 + lane * 8) = *(const uint4*)hb;
            *(uint4*)(efrag + (size_t)((g * 2 + 1) * 16 + ks) * 512 + lane * 8) = *(const uint4*)lb;
        }
        red[t] = s;
        __syncthreads();
        if (t < 32) {
            double acc = 0.0;
#pragma unroll
            for (int qq = 0; qq < 4; ++qq) acc += red[qq * 64 + t] + red[qq * 64 + 32 + t];
            enorm[g * 32 + t] = (float)acc;
        }
    }
}

// ---- MFMA argmin v14: r6 block structure, csplit 4 -> 8 for 4 blocks/CU ----
// Per-CU MFMA and LDS work invariant; occupancy 8 -> 16 waves/CU so independent
// blocks' LDS-read bursts overlap other blocks' MFMA bursts (the measured r6
// stall was intra-block read/MFMA serialization at only 2 blocks/CU).
// Resources: 124 VGPR x 4 waves/SIMD = 496 <= 512; 33.3 KB x 4 = 133 <= 160 KB.
// csplit = blockIdx&7 = XCD id under round-robin -> 1 MB efrag slice per XCD L2.
// Math/order bit-identical to r6 (same chunk sequence per csplit slice).
__global__ __launch_bounds__(256, 2) void argmin_mfma(
    const unsigned short* __restrict__ zfrag, const unsigned short* __restrict__ efrag,
    const float* __restrict__ enorm, unsigned long long* __restrict__ amin) {
    __shared__ __align__(16) unsigned short E[2][8192];   // [buf][slot(lv*2+cg)*4+ksl][lane*8]
    __shared__ float en_s[2][64];

    const int tid = threadIdx.x, lane = tid & 63, wave = tid >> 6;
    const int csplit = blockIdx.x & 7, tile = blockIdx.x >> 3;
    const int token0 = tile * 128, code0 = csplit * 1024;

    // register-resident Z frags for this wave's 32-token group
    f16x8 Zr[2][16];
    {
        const unsigned short* zb = zfrag + (size_t)(tile * 4 + wave) * 16384 + lane * 8;
#pragma unroll
        for (int lv = 0; lv < 2; ++lv)
#pragma unroll
            for (int ks = 0; ks < 16; ++ks)
                Zr[lv][ks] = *(const f16x8*)(zb + (lv * 16 + ks) * 512);
    }

    const int slv = wave >> 1, scg = wave & 1;   // this wave stages (level slv, code-group scg)

    float bv = 3.4e38f; int bi = 0;

    // prologue: chunk (ct=0, kc=0) -> buf 0; en_s[0]
#pragma unroll
    for (int ksl = 0; ksl < 4; ++ksl) {
        const unsigned short* sp = efrag +
            (size_t)(((csplit * 32 + scg) * 2 + slv) * 16 + ksl) * 512 + lane * 8;
        GLD16(sp, &E[0][(wave * 4 + ksl) * 512]);
    }
    if (tid < 64) en_s[0][tid] = enorm[code0 + tid];
    __syncthreads();

    for (int ct = 0; ct < 16; ++ct) {
        f32x16 acc_h[2], acc_l[2];
#pragma unroll
        for (int cg = 0; cg < 2; ++cg)
#pragma unroll
            for (int qq = 0; qq < 16; ++qq) { acc_h[cg][qq] = 0.f; acc_l[cg][qq] = 0.f; }

#pragma unroll
        for (int kc = 0; kc < 4; ++kc) {
            const int p = (ct * 4 + kc) & 1;
            if (!(ct == 15 && kc == 3)) {
                const int nch = ct * 4 + kc + 1;
                const int nct = nch >> 2, nkc = nch & 3;
                const int g = csplit * 32 + nct * 2 + scg;
#pragma unroll
                for (int ksl = 0; ksl < 4; ++ksl) {
                    const unsigned short* sp = efrag +
                        (size_t)((g * 2 + slv) * 16 + nkc * 4 + ksl) * 512 + lane * 8;
                    GLD16(sp, &E[p ^ 1][(wave * 4 + ksl) * 512]);
                }
            }
            if (kc == 0 && ct < 15 && tid < 64)
                en_s[(ct + 1) & 1][tid] = enorm[code0 + (ct + 1) * 64 + tid];

#pragma unroll
            for (int ksl = 0; ksl < 4; ++ksl) {
                const int ks = kc * 4 + ksl;
                f16x8 ae[2][2];
#pragma unroll
                for (int lv = 0; lv < 2; ++lv)
#pragma unroll
                    for (int cg = 0; cg < 2; ++cg)
                        ae[lv][cg] = *(const f16x8*)&E[p][((lv * 2 + cg) * 4 + ksl) * 512 + lane * 8];
                // three passes; per-accumulator order identical to the proven kernel
#pragma unroll
                for (int cg = 0; cg < 2; ++cg)
                    acc_h[cg] = __builtin_amdgcn_mfma_f32_32x32x16_f16(ae[0][cg], Zr[0][ks], acc_h[cg], 0, 0, 0);
#pragma unroll
                for (int cg = 0; cg < 2; ++cg)
                    acc_l[cg] = __builtin_amdgcn_mfma_f32_32x32x16_f16(ae[0][cg], Zr[1][ks], acc_l[cg], 0, 0, 0);
#pragma unroll
                for (int cg = 0; cg < 2; ++cg)
                    acc_l[cg] = __builtin_amdgcn_mfma_f32_32x32x16_f16(ae[1][cg], Zr[0][ks], acc_l[cg], 0, 0, 0);
            }
            if (kc == 3) {
                // score = ||e||^2 - 2*(hi + lo/2048); per-lane running argmin (k ascending)
                const int rbase = 4 * (lane >> 5);
#pragma unroll
                for (int cg = 0; cg < 2; ++cg)
#pragma unroll
                    for (int r = 0; r < 16; ++r) {
                        const int cl = cg * 32 + (r & 3) + 8 * (r >> 2) + rbase;
                        const float s = en_s[ct & 1][cl] -
                            2.0f * (acc_h[cg][r] + acc_l[cg][r] * 4.8828125e-4f);
                        const int code = code0 + ct * 64 + cl;
                        if (s < bv) { bv = s; bi = code; }
                    }
            }
            __syncthreads();
        }
    }
    // lanes l and l^32 hold the same token (different code row-halves)
    {
        const float ov = __shfl_xor(bv, 32);
        const int   oi = __shfl_xor(bi, 32);
        if (ov < bv || (ov == bv && oi < bi)) { bv = ov; bi = oi; }
    }
    if (lane < 32) {
        const int n = token0 + wave * 32 + lane;
        unsigned int u = __float_as_uint(bv);
        u = (u & 0x80000000u) ? ~u : (u | 0x80000000u);   // order-preserving f32->u32
        const unsigned long long pk = ((unsigned long long)u << 32) | (unsigned int)bi;
        atomicMin(&amin[n], pk);
    }
}

// ---- unpack packed argmin -> idx_i / idx_f + per-code counts ----
__global__ __launch_bounds__(256) void idx_cnt_kernel(
    const unsigned long long* __restrict__ amin,
    int* __restrict__ idx_i, float* __restrict__ idx_f, int* __restrict__ cnt) {
    const int n = blockIdx.x * 256 + threadIdx.x;
    const int bi = (int)(unsigned int)(amin[n] & 0xFFFFFFFFull);
    idx_i[n] = bi;
    idx_f[n] = (float)bi;
    atomicAdd(&cnt[bi], 1);
}

// ---- exclusive scan of 8192 counts (single block) ----
__global__ __launch_bounds__(256) void scan_kernel(const int* __restrict__ cnt,
                                                   int* __restrict__ offs,
                                                   int* __restrict__ wpos) {
    __shared__ int part[256];
    const int tid = threadIdx.x;
    const int base = tid * 32;
    int loc[32];
    int s = 0;
#pragma unroll
    for (int j = 0; j < 32; ++j) { loc[j] = cnt[base + j]; s += loc[j]; }
    part[tid] = s;
    __syncthreads();
    for (int off = 1; off < 256; off <<= 1) {
        int v = 0;
        if (tid >= off) v = part[tid - off];
        __syncthreads();
        if (tid >= off) part[tid] += v;
        __syncthreads();
    }
    int run = (tid > 0) ? part[tid - 1] : 0;
#pragma unroll
    for (int j = 0; j < 32; ++j) {
        offs[base + j] = run;
        wpos[base + j] = run;
        run += loc[j];
    }
}

// ---- fused: scatter token ids (blocks 0-63) + cs/denom (blocks 64-95) ----
__global__ __launch_bounds__(256) void scatter_cs(
    const int* __restrict__ idx_i, int* __restrict__ wpos, int* __restrict__ tlist,
    const float* __restrict__ cluster_size, const int* __restrict__ cnt,
    float* __restrict__ cs, double* __restrict__ denom) {
    __shared__ double red[256];
    const int t = threadIdx.x, b = blockIdx.x;
    if (b < 64) {
        const int n = b * 256 + t;
        const int k = idx_i[n];
        tlist[atomicAdd(&wpos[k], 1)] = n;
    } else {
        const int k = (b - 64) * 256 + t;
        const float v = cluster_size[k] * 0.99f + 0.01f * (float)cnt[k] + 1e-5f;
        cs[k] = v;
        red[t] = (double)v;
        __syncthreads();
        for (int s2 = 128; s2; s2 >>= 1) {
            if (t < s2) red[t] += red[t + s2];
            __syncthreads();
        }
        if (t == 0) atomicAdd(denom, red[0]);
    }
}

// ---- fused: nema_finalize (blocks 0-2047, 4 codes each) + gather/loss (2048-3071) ----
__global__ __launch_bounds__(256) void nema_gather(
    const unsigned short* __restrict__ zfrag,
    const int* __restrict__ offs, const int* __restrict__ cnt, const int* __restrict__ tlist,
    const float* __restrict__ ema_w, const float* __restrict__ cs,
    const double* __restrict__ denom, float* __restrict__ ncs_out,
    float* __restrict__ nema_out, float* __restrict__ nemb_out,
    const float* __restrict__ z, const float* __restrict__ emb,
    const int* __restrict__ idx_i, float* __restrict__ out, float* __restrict__ loss_cell) {
    __shared__ float redf[256];
    const int t = threadIdx.x;
    if (blockIdx.x < 2048) {
        const int lane = t & 63, wave = t >> 6;
        const int k = blockIdx.x * 4 + wave;
        const int l31 = lane & 31, sel = lane >> 5;  // sel: 0 = hi loader, 1 = lo loader
        const int beg = offs[k], c = cnt[k];
        float acc[8] = {0.f, 0.f, 0.f, 0.f, 0.f, 0.f, 0.f, 0.f};
        const size_t lidx = (size_t)((l31 >> 1) + sel * 16) * 512 + (l31 & 1) * 256;
        int i = 0;
        for (; i + 1 < c; i += 2) {      // 2-way unroll: independent load/shfl chains
            const int tokA = tlist[beg + i], tokB = tlist[beg + i + 1];
            const uint4 vA = *(const uint4*)(zfrag + (size_t)(tokA >> 5) * 16384 + lidx + (tokA & 31) * 8);
            const uint4 vB = *(const uint4*)(zfrag + (size_t)(tokB >> 5) * 16384 + lidx + (tokB & 31) * 8);
            uint4 oA, oB;
            oA.x = __shfl_xor((int)vA.x, 32); oA.y = __shfl_xor((int)vA.y, 32);
            oA.z = __shfl_xor((int)vA.z, 32); oA.w = __shfl_xor((int)vA.w, 32);
            oB.x = __shfl_xor((int)vB.x, 32); oB.y = __shfl_xor((int)vB.y, 32);
            oB.z = __shfl_xor((int)vB.z, 32); oB.w = __shfl_xor((int)vB.w, 32);
            if (lane < 32) {
                const unsigned short* hA = (const unsigned short*)&vA;
                const unsigned short* lA = (const unsigned short*)&oA;
                const unsigned short* hB = (const unsigned short*)&vB;
                const unsigned short* lB = (const unsigned short*)&oB;
#pragma unroll
                for (int j = 0; j < 8; ++j)
                    acc[j] += join_f16(hA[j], lA[j]) + join_f16(hB[j], lB[j]);
            }
        }
        if (i < c) {
            const int tok = tlist[beg + i];
            const uint4 v = *(const uint4*)(zfrag + (size_t)(tok >> 5) * 16384 + lidx + (tok & 31) * 8);
            uint4 o;
            o.x = __shfl_xor((int)v.x, 32); o.y = __shfl_xor((int)v.y, 32);
            o.z = __shfl_xor((int)v.z, 32); o.w = __shfl_xor((int)v.w, 32);
            if (lane < 32) {
                const unsigned short* hp = (const unsigned short*)&v;
                const unsigned short* lp = (const unsigned short*)&o;
#pragma unroll
                for (int j = 0; j < 8; ++j) acc[j] += join_f16(hp[j], lp[j]);
            }
        }
        const float dn = (float)(*denom) + (float)K_CODES * 1e-5f;
        const float ncs = cs[k] / dn;
        if (lane == 0) ncs_out[k] = ncs;
        if (lane < 32) {
            const size_t off = ((size_t)k << 8) + l31 * 8;
#pragma unroll
            for (int j = 0; j < 8; ++j) {
                const float ne = ema_w[off + j] * 0.99f + 0.01f * acc[j];
                nema_out[off + j] = ne;
                nemb_out[off + j] = ne / ncs;
            }
        }
    } else {
        const int gb = blockIdx.x - 2048;
        const int n0 = (gb >> 2) * 64;
        const int dg = (gb & 3) * 64;
        const int b = n0 >> 10, hw0 = n0 & 1023;
        const int lane = t & 63, w = t >> 6;
        const int n = n0 + lane;
        const int k = idx_i[n];
        const float* zb = z + ((size_t)b << 18) + hw0 + lane;
        float* ob = out + ((size_t)b << 18) + hw0 + lane;
        float ls = 0.f;
#pragma unroll 4
        for (int d = dg + w; d < dg + 64; d += 4) {
            const float zv = zb[(size_t)d << 10];
            const float ev = emb[((size_t)k << 8) + d];
            ob[(size_t)d << 10] = ev;
            const float df = ev - zv;
            ls += df * df;
        }
        redf[t] = ls;
        __syncthreads();
        for (int s2 = 128; s2; s2 >>= 1) {
            if (t < s2) redf[t] += redf[t + s2];
            __syncthreads();
        }
        if (t == 0) atomicAdd(loss_cell, redf[0] * (0.25f / 4194304.0f));
    }
}

// ---------------- launch ----------------
extern "C" void kernel_launch(void* const* d_in, const int* in_sizes, int n_in,
                              void* d_out, int out_size, void* d_ws, size_t ws_size,
                              hipStream_t stream) {
    const float* z            = (const float*)d_in[0];
    const float* emb          = (const float*)d_in[1];
    const float* cluster_size = (const float*)d_in[2];
    const float* ema_w        = (const float*)d_in[3];
    float* out = (float*)d_out;
    char*  wsb = (char*)d_ws;

    unsigned short* zfrag = (unsigned short*)(wsb + WS_ZFRAG);
    unsigned short* efrag = (unsigned short*)(wsb + WS_EFRAG);
    float*  enorm  = (float*)(wsb + WS_ENORM);
    unsigned long long* amin = (unsigned long long*)(wsb + WS_AMIN);
    int*    idx_i  = (int*)(wsb + WS_IDXI);
    int*    cnt    = (int*)(wsb + WS_CNT);
    float*  cs     = (float*)(wsb + WS_CS);
    int*    offs   = (int*)(wsb + WS_OFFS);
    int*    wpos   = (int*)(wsb + WS_WPOS);
    int*    tlist  = (int*)(wsb + WS_TLIST);
    double* denom  = (double*)(wsb + WS_DENOM);

    fused_cvt<<<1280, 256, 0, stream>>>(z, zfrag, out + LOSS_OFF, denom,
                                        emb, efrag, enorm, cnt, amin);
    argmin_mfma<<<1024, 256, 0, stream>>>(zfrag, efrag, enorm, amin);
    idx_cnt_kernel<<<N_TOK / 256, 256, 0, stream>>>(amin, idx_i, out + IDX_OFF, cnt);
    scan_kernel<<<1, 256, 0, stream>>>(cnt, offs, wpos);
    scatter_cs<<<96, 256, 0, stream>>>(idx_i, wpos, tlist, cluster_size, cnt, cs, denom);
    nema_gather<<<3072, 256, 0, stream>>>(zfrag, offs, cnt, tlist, ema_w, cs, denom,
                                          out + NCS_OFF, out + NEMA_OFF, out + NEMB_OFF,
                                          z, emb, idx_i, out + OUT_OFF, out + LOSS_OFF);
}

// Round 10
// 373.693 us; speedup vs baseline: 1.0884x; 1.0081x over previous
//
#include <hip/hip_runtime.h>

#define N_TOK   16384
#define K_CODES 8192
#define DIMS    256

// d_out offsets (floats): out, loss, idx, new_cluster_size, new_ema_w, new_embedding
#define OUT_OFF  0
#define LOSS_OFF 4194304
#define IDX_OFF  4194305
#define NCS_OFF  4210689
#define NEMA_OFF 4218881
#define NEMB_OFF 6316033

// ws byte offsets
#define WS_ZFRAG  0u          // ushort frag-order [512 tg][2 lv][16 ks][64 lane][8] = 16 MB
#define WS_EFRAG  16777216u   // ushort frag-order [256 g][2 lv][16 ks][64 lane][8] = 8 MB
#define WS_ENORM  25165824u   // f32 [8192]
#define WS_AMIN   25198592u   // u64 [16384] packed (score|idx) argmin cells
#define WS_IDXI   25722880u   // int [16384]
#define WS_CNT    25788416u   // int [8192]
#define WS_CS     25821184u   // f32 [8192]
#define WS_OFFS   25853952u   // int [8192]
#define WS_WPOS   25886720u   // int [8192]
#define WS_TLIST  25919488u   // int [16384]
#define WS_DENOM  25985024u   // double

typedef _Float16 f16x8 __attribute__((ext_vector_type(8)));
typedef float    f32x16 __attribute__((ext_vector_type(16)));

union HU { _Float16 h; unsigned short u; };

static __device__ inline void split_f32(float x, unsigned short& hi, unsigned short& lo) {
    HU a; a.h = (_Float16)x;                    // RNE f32->f16
    float r = (x - (float)a.h) * 2048.0f;       // exact residual, scaled to normal range
    HU b; b.h = (_Float16)r;
    hi = a.u; lo = b.u;
}

static __device__ inline float join_f16(unsigned short h, unsigned short l) {
    HU a, b; a.u = h; b.u = l;
    return (float)a.h + (float)b.h * 4.8828125e-4f;
}

// async global->LDS, 16B per lane; LDS dest = wave-uniform base + lane*16
#define GLD16(gp, lp) __builtin_amdgcn_global_load_lds( \
    (const __attribute__((address_space(1))) unsigned int*)(gp), \
    (__attribute__((address_space(3))) unsigned int*)(lp), 16, 0, 0)

// ---- fused: cvt_z (blocks 0-1023) + cvt_e/enorm/init (blocks 1024-1279) ----
__global__ __launch_bounds__(256) void fused_cvt(
    const float* __restrict__ z, unsigned short* __restrict__ zfrag,
    float* __restrict__ loss_cell, double* __restrict__ denom,
    const float* __restrict__ emb, unsigned short* __restrict__ efrag,
    float* __restrict__ enorm, int* __restrict__ cnt,
    unsigned long long* __restrict__ amin) {
    const int t = threadIdx.x;
    if (blockIdx.x < 1024) {
        // ---- cvt_z: z [16][256][1024] f32 -> zfrag (frag-order, 2-level split) ----
        __shared__ float T[64][65];
        const int hg = blockIdx.x & 15, dg = (blockIdx.x >> 4) & 3, b = blockIdx.x >> 6;
        if (blockIdx.x == 0 && t == 0) { *loss_cell = 0.f; *denom = 0.0; }
        const int c4 = (t & 15) * 4, r0 = t >> 4;
        const float* zb = z + (((size_t)(b * 256 + dg * 64)) << 10) + hg * 64;
#pragma unroll
        for (int p = 0; p < 4; ++p) {
            const int r = r0 + p * 16;
            const float4 v = *(const float4*)(zb + ((size_t)r << 10) + c4);
            T[r][c4] = v.x; T[r][c4 + 1] = v.y; T[r][c4 + 2] = v.z; T[r][c4 + 3] = v.w;
        }
        __syncthreads();
        const int tr = t & 63, dc = (t >> 6) * 16;   // token-local tr, 16-dim chunk dc
        const int tile = b * 16 + hg;
        const int tg = tile * 2 + (tr >> 5), l31 = tr & 31;
        const int ks = dg * 4 + (dc >> 4);
        unsigned short hb[16], lb[16];
#pragma unroll
        for (int j = 0; j < 16; ++j) split_f32(T[dc + j][tr], hb[j], lb[j]);
#pragma unroll
        for (int lv = 0; lv < 2; ++lv) {
            const unsigned short* src = lv ? lb : hb;
            unsigned short* dst = zfrag + (size_t)((tg * 2 + lv) * 16 + ks) * 512;
            *(uint4*)(dst + l31 * 8)       = ((const uint4*)src)[0];   // khalf 0 (j 0..7)
            *(uint4*)(dst + 256 + l31 * 8) = ((const uint4*)src)[1];   // khalf 1 (j 8..15)
        }
    } else {
        // ---- cvt_e: emb -> efrag + ||e||^2 (f64); zero cnt; init amin to +inf ----
        __shared__ double red[256];
        const int g = blockIdx.x - 1024;
        const int lane = t & 63, q = t >> 6;
        const int l31 = lane & 31, lhi = lane >> 5;
        if (g < 32) cnt[g * 256 + t] = 0;
        if (g < 64) amin[g * 256 + t] = 0xFFFFFFFFFFFFFFFFull;
        const float* rowp = emb + (size_t)(g * 32 + l31) * 256 + lhi * 8;
        double s = 0.0;
#pragma unroll
        for (int kk = 0; kk < 4; ++kk) {
            const int ks = q * 4 + kk;
            const float4 a = *(const float4*)(rowp + ks * 16);
            const float4 bq = *(const float4*)(rowp + ks * 16 + 4);
            const float vv[8] = {a.x, a.y, a.z, a.w, bq.x, bq.y, bq.z, bq.w};
            unsigned short hb[8], lb[8];
#pragma unroll
            for (int j = 0; j < 8; ++j) {
                split_f32(vv[j], hb[j], lb[j]);
                s += (double)vv[j] * (double)vv[j];
            }
            *(uint4*)(efrag + (size_t)((g * 2 + 0) * 16 + ks) * 512 + lane * 8) = *(const uint4*)hb;
            *(uint4*)(efrag + (size_t)((g * 2 + 1) * 16 + ks) * 512 + lane * 8) = *(const uint4*)lb;
        }
        red[t] = s;
        __syncthreads();
        if (t < 32) {
            double acc = 0.0;
#pragma unroll
            for (int qq = 0; qq < 4; ++qq) acc += red[qq * 64 + t] + red[qq * 64 + 32 + t];
            enorm[g * 32 + t] = (float)acc;
        }
    }
}

// ---- MFMA argmin v15: r6 structure with COARSER PHASES (64 barriers, not 128) ----
// Each phase stages 32 KB (64 codes x 128 dims x 2 levels) instead of 16 KB and
// runs 48 MFMAs + 32 ds_reads + 8 GLD16 per wave -- 2x independent work per
// barrier interval for the scheduler to interleave, and the full-drain barrier
// cost is paid half as often. Registers (124+64 unified -> 2 waves/SIMD cap,
// r9 diagnosis), math, and per-accumulator MFMA order bit-identical to r6.
// LDS 64.5 KB/block: 2 blocks/CU still fit (129 <= 160 KB).
__global__ __launch_bounds__(256, 2) void argmin_mfma(
    const unsigned short* __restrict__ zfrag, const unsigned short* __restrict__ efrag,
    const float* __restrict__ enorm, unsigned long long* __restrict__ amin) {
    __shared__ __align__(16) unsigned short E[2][16384];  // [buf][slot(lv*2+cg)*8+ksl][lane*8]
    __shared__ float en_s[2][64];

    const int tid = threadIdx.x, lane = tid & 63, wave = tid >> 6;
    const int tile = blockIdx.x & 127, csplit = blockIdx.x >> 7;
    const int token0 = tile * 128, code0 = csplit * 2048;

    // register-resident Z frags for this wave's 32-token group
    f16x8 Zr[2][16];
    {
        const unsigned short* zb = zfrag + (size_t)(tile * 4 + wave) * 16384 + lane * 8;
#pragma unroll
        for (int lv = 0; lv < 2; ++lv)
#pragma unroll
            for (int ks = 0; ks < 16; ++ks)
                Zr[lv][ks] = *(const f16x8*)(zb + (lv * 16 + ks) * 512);
    }

    const int slv = wave >> 1, scg = wave & 1;   // this wave stages (level slv, code-group scg)

    // stage chunk ch (= ct*2 + khalf) into buffer ch&1: 8 GLD16/wave (32 KB block-wide)
    auto stage = [&](int ch, int buf) {
        const int nct = ch >> 1, nkh = ch & 1;
        const int g = csplit * 64 + nct * 2 + scg;
#pragma unroll
        for (int ksl = 0; ksl < 8; ++ksl) {
            const unsigned short* sp = efrag +
                (size_t)((g * 2 + slv) * 16 + nkh * 8 + ksl) * 512 + lane * 8;
            GLD16(sp, &E[buf][(wave * 8 + ksl) * 512]);
        }
    };

    float bv = 3.4e38f; int bi = 0;

    // prologue: chunk 0 -> buf 0; en_s[0]
    stage(0, 0);
    if (tid < 64) en_s[0][tid] = enorm[code0 + tid];
    __syncthreads();

    for (int ct = 0; ct < 32; ++ct) {
        f32x16 acc_h[2], acc_l[2];
#pragma unroll
        for (int cg = 0; cg < 2; ++cg)
#pragma unroll
            for (int qq = 0; qq < 16; ++qq) { acc_h[cg][qq] = 0.f; acc_l[cg][qq] = 0.f; }

#pragma unroll
        for (int kh = 0; kh < 2; ++kh) {
            const int p = kh;                       // ct*2 even -> (ct*2+kh)&1 == kh
            if (!(ct == 31 && kh == 1)) stage(ct * 2 + kh + 1, p ^ 1);
            if (kh == 0 && ct < 31 && tid < 64)
                en_s[(ct + 1) & 1][tid] = enorm[code0 + (ct + 1) * 64 + tid];

#pragma unroll
            for (int ksl = 0; ksl < 8; ++ksl) {
                const int ks = kh * 8 + ksl;
                f16x8 ae[2][2];
#pragma unroll
                for (int lv = 0; lv < 2; ++lv)
#pragma unroll
                    for (int cg = 0; cg < 2; ++cg)
                        ae[lv][cg] = *(const f16x8*)&E[p][((lv * 2 + cg) * 8 + ksl) * 512 + lane * 8];
                // three passes; per-accumulator order identical to the proven kernel
#pragma unroll
                for (int cg = 0; cg < 2; ++cg)
                    acc_h[cg] = __builtin_amdgcn_mfma_f32_32x32x16_f16(ae[0][cg], Zr[0][ks], acc_h[cg], 0, 0, 0);
#pragma unroll
                for (int cg = 0; cg < 2; ++cg)
                    acc_l[cg] = __builtin_amdgcn_mfma_f32_32x32x16_f16(ae[0][cg], Zr[1][ks], acc_l[cg], 0, 0, 0);
#pragma unroll
                for (int cg = 0; cg < 2; ++cg)
                    acc_l[cg] = __builtin_amdgcn_mfma_f32_32x32x16_f16(ae[1][cg], Zr[0][ks], acc_l[cg], 0, 0, 0);
            }
            if (kh == 1) {
                // score = ||e||^2 - 2*(hi + lo/2048); per-lane running argmin (k ascending)
                const int rbase = 4 * (lane >> 5);
#pragma unroll
                for (int cg = 0; cg < 2; ++cg)
#pragma unroll
                    for (int r = 0; r < 16; ++r) {
                        const int cl = cg * 32 + (r & 3) + 8 * (r >> 2) + rbase;
                        const float s = en_s[ct & 1][cl] -
                            2.0f * (acc_h[cg][r] + acc_l[cg][r] * 4.8828125e-4f);
                        const int code = code0 + ct * 64 + cl;
                        if (s < bv) { bv = s; bi = code; }
                    }
            }
            __syncthreads();
        }
    }
    // lanes l and l^32 hold the same token (different code row-halves)
    {
        const float ov = __shfl_xor(bv, 32);
        const int   oi = __shfl_xor(bi, 32);
        if (ov < bv || (ov == bv && oi < bi)) { bv = ov; bi = oi; }
    }
    if (lane < 32) {
        const int n = token0 + wave * 32 + lane;
        unsigned int u = __float_as_uint(bv);
        u = (u & 0x80000000u) ? ~u : (u | 0x80000000u);   // order-preserving f32->u32
        const unsigned long long pk = ((unsigned long long)u << 32) | (unsigned int)bi;
        atomicMin(&amin[n], pk);
    }
}

// ---- unpack packed argmin -> idx_i / idx_f + per-code counts ----
__global__ __launch_bounds__(256) void idx_cnt_kernel(
    const unsigned long long* __restrict__ amin,
    int* __restrict__ idx_i, float* __restrict__ idx_f, int* __restrict__ cnt) {
    const int n = blockIdx.x * 256 + threadIdx.x;
    const int bi = (int)(unsigned int)(amin[n] & 0xFFFFFFFFull);
    idx_i[n] = bi;
    idx_f[n] = (float)bi;
    atomicAdd(&cnt[bi], 1);
}

// ---- exclusive scan of 8192 counts (single block) ----
__global__ __launch_bounds__(256) void scan_kernel(const int* __restrict__ cnt,
                                                   int* __restrict__ offs,
                                                   int* __restrict__ wpos) {
    __shared__ int part[256];
    const int tid = threadIdx.x;
    const int base = tid * 32;
    int loc[32];
    int s = 0;
#pragma unroll
    for (int j = 0; j < 32; ++j) { loc[j] = cnt[base + j]; s += loc[j]; }
    part[tid] = s;
    __syncthreads();
    for (int off = 1; off < 256; off <<= 1) {
        int v = 0;
        if (tid >= off) v = part[tid - off];
        __syncthreads();
        if (tid >= off) part[tid] += v;
        __syncthreads();
    }
    int run = (tid > 0) ? part[tid - 1] : 0;
#pragma unroll
    for (int j = 0; j < 32; ++j) {
        offs[base + j] = run;
        wpos[base + j] = run;
        run += loc[j];
    }
}

// ---- fused: scatter token ids (blocks 0-63) + cs/denom (blocks 64-95) ----
__global__ __launch_bounds__(256) void scatter_cs(
    const int* __restrict__ idx_i, int* __restrict__ wpos, int* __restrict__ tlist,
    const float* __restrict__ cluster_size, const int* __restrict__ cnt,
    float* __restrict__ cs, double* __restrict__ denom) {
    __shared__ double red[256];
    const int t = threadIdx.x, b = blockIdx.x;
    if (b < 64) {
        const int n = b * 256 + t;
        const int k = idx_i[n];
        tlist[atomicAdd(&wpos[k], 1)] = n;
    } else {
        const int k = (b - 64) * 256 + t;
        const float v = cluster_size[k] * 0.99f + 0.01f * (float)cnt[k] + 1e-5f;
        cs[k] = v;
        red[t] = (double)v;
        __syncthreads();
        for (int s2 = 128; s2; s2 >>= 1) {
            if (t < s2) red[t] += red[t + s2];
            __syncthreads();
        }
        if (t == 0) atomicAdd(denom, red[0]);
    }
}

// ---- fused: nema_finalize (blocks 0-2047, 4 codes each) + gather/loss (2048-3071) ----
__global__ __launch_bounds__(256) void nema_gather(
    const unsigned short* __restrict__ zfrag,
    const int* __restrict__ offs, const int* __restrict__ cnt, const int* __restrict__ tlist,
    const float* __restrict__ ema_w, const float* __restrict__ cs,
    const double* __restrict__ denom, float* __restrict__ ncs_out,
    float* __restrict__ nema_out, float* __restrict__ nemb_out,
    const float* __restrict__ z, const float* __restrict__ emb,
    const int* __restrict__ idx_i, float* __restrict__ out, float* __restrict__ loss_cell) {
    __shared__ float redf[256];
    const int t = threadIdx.x;
    if (blockIdx.x < 2048) {
        const int lane = t & 63, wave = t >> 6;
        const int k = blockIdx.x * 4 + wave;
        const int l31 = lane & 31, sel = lane >> 5;  // sel: 0 = hi loader, 1 = lo loader
        const int beg = offs[k], c = cnt[k];
        float acc[8] = {0.f, 0.f, 0.f, 0.f, 0.f, 0.f, 0.f, 0.f};
        const size_t lidx = (size_t)((l31 >> 1) + sel * 16) * 512 + (l31 & 1) * 256;
        int i = 0;
        for (; i + 1 < c; i += 2) {      // 2-way unroll: independent load/shfl chains
            const int tokA = tlist[beg + i], tokB = tlist[beg + i + 1];
            const uint4 vA = *(const uint4*)(zfrag + (size_t)(tokA >> 5) * 16384 + lidx + (tokA & 31) * 8);
            const uint4 vB = *(const uint4*)(zfrag + (size_t)(tokB >> 5) * 16384 + lidx + (tokB & 31) * 8);
            uint4 oA, oB;
            oA.x = __shfl_xor((int)vA.x, 32); oA.y = __shfl_xor((int)vA.y, 32);
            oA.z = __shfl_xor((int)vA.z, 32); oA.w = __shfl_xor((int)vA.w, 32);
            oB.x = __shfl_xor((int)vB.x, 32); oB.y = __shfl_xor((int)vB.y, 32);
            oB.z = __shfl_xor((int)vB.z, 32); oB.w = __shfl_xor((int)vB.w, 32);
            if (lane < 32) {
                const unsigned short* hA = (const unsigned short*)&vA;
                const unsigned short* lA = (const unsigned short*)&oA;
                const unsigned short* hB = (const unsigned short*)&vB;
                const unsigned short* lB = (const unsigned short*)&oB;
#pragma unroll
                for (int j = 0; j < 8; ++j)
                    acc[j] += join_f16(hA[j], lA[j]) + join_f16(hB[j], lB[j]);
            }
        }
        if (i < c) {
            const int tok = tlist[beg + i];
            const uint4 v = *(const uint4*)(zfrag + (size_t)(tok >> 5) * 16384 + lidx + (tok & 31) * 8);
            uint4 o;
            o.x = __shfl_xor((int)v.x, 32); o.y = __shfl_xor((int)v.y, 32);
            o.z = __shfl_xor((int)v.z, 32); o.w = __shfl_xor((int)v.w, 32);
            if (lane < 32) {
                const unsigned short* hp = (const unsigned short*)&v;
                const unsigned short* lp = (const unsigned short*)&o;
#pragma unroll
                for (int j = 0; j < 8; ++j) acc[j] += join_f16(hp[j], lp[j]);
            }
        }
        const float dn = (float)(*denom) + (float)K_CODES * 1e-5f;
        const float ncs = cs[k] / dn;
        if (lane == 0) ncs_out[k] = ncs;
        if (lane < 32) {
            const size_t off = ((size_t)k << 8) + l31 * 8;
#pragma unroll
            for (int j = 0; j < 8; ++j) {
                const float ne = ema_w[off + j] * 0.99f + 0.01f * acc[j];
                nema_out[off + j] = ne;
                nemb_out[off + j] = ne / ncs;
            }
        }
    } else {
        const int gb = blockIdx.x - 2048;
        const int n0 = (gb >> 2) * 64;
        const int dg = (gb & 3) * 64;
        const int b = n0 >> 10, hw0 = n0 & 1023;
        const int lane = t & 63, w = t >> 6;
        const int n = n0 + lane;
        const int k = idx_i[n];
        const float* zb = z + ((size_t)b << 18) + hw0 + lane;
        float* ob = out + ((size_t)b << 18) + hw0 + lane;
        float ls = 0.f;
#pragma unroll 4
        for (int d = dg + w; d < dg + 64; d += 4) {
            const float zv = zb[(size_t)d << 10];
            const float ev = emb[((size_t)k << 8) + d];
            ob[(size_t)d << 10] = ev;
            const float df = ev - zv;
            ls += df * df;
        }
        redf[t] = ls;
        __syncthreads();
        for (int s2 = 128; s2; s2 >>= 1) {
            if (t < s2) redf[t] += redf[t + s2];
            __syncthreads();
        }
        if (t == 0) atomicAdd(loss_cell, redf[0] * (0.25f / 4194304.0f));
    }
}

// ---------------- launch ----------------
extern "C" void kernel_launch(void* const* d_in, const int* in_sizes, int n_in,
                              void* d_out, int out_size, void* d_ws, size_t ws_size,
                              hipStream_t stream) {
    const float* z            = (const float*)d_in[0];
    const float* emb          = (const float*)d_in[1];
    const float* cluster_size = (const float*)d_in[2];
    const float* ema_w        = (const float*)d_in[3];
    float* out = (float*)d_out;
    char*  wsb = (char*)d_ws;

    unsigned short* zfrag = (unsigned short*)(wsb + WS_ZFRAG);
    unsigned short* efrag = (unsigned short*)(wsb + WS_EFRAG);
    float*  enorm  = (float*)(wsb + WS_ENORM);
    unsigned long long* amin = (unsigned long long*)(wsb + WS_AMIN);
    int*    idx_i  = (int*)(wsb + WS_IDXI);
    int*    cnt    = (int*)(wsb + WS_CNT);
    float*  cs     = (float*)(wsb + WS_CS);
    int*    offs   = (int*)(wsb + WS_OFFS);
    int*    wpos   = (int*)(wsb + WS_WPOS);
    int*    tlist  = (int*)(wsb + WS_TLIST);
    double* denom  = (double*)(wsb + WS_DENOM);

    fused_cvt<<<1280, 256, 0, stream>>>(z, zfrag, out + LOSS_OFF, denom,
                                        emb, efrag, enorm, cnt, amin);
    argmin_mfma<<<512, 256, 0, stream>>>(zfrag, efrag, enorm, amin);
    idx_cnt_kernel<<<N_TOK / 256, 256, 0, stream>>>(amin, idx_i, out + IDX_OFF, cnt);
    scan_kernel<<<1, 256, 0, stream>>>(cnt, offs, wpos);
    scatter_cs<<<96, 256, 0, stream>>>(idx_i, wpos, tlist, cluster_size, cnt, cs, denom);
    nema_gather<<<3072, 256, 0, stream>>>(zfrag, offs, cnt, tlist, ema_w, cs, denom,
                                          out + NCS_OFF, out + NEMA_OFF, out + NEMB_OFF,
                                          z, emb, idx_i, out + OUT_OFF, out + LOSS_OFF);
}